// Round 6
// baseline (4758.613 us; speedup 1.0000x reference)
//
#include <hip/hip_runtime.h>

#define B_   256
#define T_   512
#define IN_  34
#define H_   80
#define L_   10
#define NC_  5
#define G4   320
#define TPB  640        // 80 elements x 8 K-slices
#define CH   256        // chunk timesteps held in LDS
#define NCH  2          // T_/CH
#define NWF  (L_ * 20 * TPB * 4)   // packed weight floats = 512000

__device__ __forceinline__ float sigm(float x)     { return 1.f / (1.f + __expf(-x)); }
__device__ __forceinline__ float tanhfast(float x) { return 1.f - 2.f / (__expf(2.f * x) + 1.f); }

template <int CTRL>
__device__ __forceinline__ float dpp_add(float v) {
    int o = __builtin_amdgcn_update_dpp(0, __float_as_int(v), CTRL, 0xF, 0xF, true);
    return v + __int_as_float(o);
}
// Full sum over the 8-lane K-slice group (lane bits 0..2). Masks {1,2,7}
// generate the group; all three are DPP (pure VALU, no LDS).
__device__ __forceinline__ float reduce8(float v) {
    v = dpp_add<0xB1>(v);    // quad_perm [1,0,3,2]  = xor 1
    v = dpp_add<0x4E>(v);    // quad_perm [2,3,0,1]  = xor 2
    v = dpp_add<0x141>(v);   // row_half_mirror      = xor 7
    return v;
}

// Pack weights thread-major for coalesced float4 loads:
// wbuf[((l*20 + i4)*TPB + tid)*4 + c] where thread tid = e*8+s owns
// gate rows {0,1,2,3}*80+e over concat-K slice [20s, 20s+20), i4 = gate*5+q.
__global__ void prep_kernel(const float* __restrict__ Wih0, const float* __restrict__ WihR,
                            const float* __restrict__ Whh,  const float* __restrict__ bih,
                            const float* __restrict__ bhh,
                            float* __restrict__ wbuf, float* __restrict__ bbuf) {
    int idx = blockIdx.x * 256 + threadIdx.x;
    if (idx < NWF) {
        int c   = idx & 3;
        int tid = (idx >> 2) % TPB;
        int i4  = ((idx >> 2) / TPB) % 20;
        int l   = idx / (4 * TPB * 20);
        int s = tid & 7, e = tid >> 3;
        int gate = i4 / 5, q = i4 % 5;
        int kc  = 20 * s + 4 * q + c;          // 0..159 over [x(80) | h(80)]
        int row = gate * H_ + e;
        float v;
        if (kc < H_) {
            if (l == 0) v = (kc < IN_) ? Wih0[row * IN_ + kc] : 0.f;
            else        v = WihR[((size_t)(l - 1) * G4 + row) * H_ + kc];
        } else {
            v = Whh[((size_t)l * G4 + row) * H_ + (kc - H_)];
        }
        wbuf[idx] = v;
    }
    if (idx < L_ * G4) bbuf[idx] = bih[idx] + bhh[idx];
}

#define PIN4(W) asm volatile("" : "+v"(W.x), "+v"(W.y), "+v"(W.z), "+v"(W.w))

__global__ __launch_bounds__(TPB, 1) void lstm_stack_kernel(
    const float* __restrict__ x,     // [B,T,34]
    const float* __restrict__ wbuf,  // packed, see prep
    const float* __restrict__ bbuf,  // [10][320]
    const float* __restrict__ fcw,   // [5,80]
    const float* __restrict__ fcb,   // [5]
    float* __restrict__ out)         // [B,5]
{
    const int b   = blockIdx.x;
    const int tid = threadIdx.x;     // 0..639
    const int s   = tid & 7;         // K-slice
    const int e   = tid >> 3;        // h element 0..79
    const int koff = 20 * (s & 3);   // float offset within hist-row / hs

    __shared__ __align__(16) float hist[CH][H_];   // 80 KB: x chunk / h history (in-place)
    __shared__ __align__(16) float hs[2][H_];      // h(t-1) ping-pong
    __shared__ float hstate[L_][H_];
    __shared__ float cstate[L_][H_];

    for (int j = tid; j < L_ * H_; j += TPB) {
        (&hstate[0][0])[j] = 0.f;
        (&cstate[0][0])[j] = 0.f;
    }

    for (int c = 0; c < NCH; ++c) {
        __syncthreads();
        // stage x chunk into hist, zero-padded 34 -> 80
        const float* xsrc = x + ((size_t)b * T_ + (size_t)c * CH) * IN_;
        for (int j = tid; j < CH * IN_; j += TPB) hist[j / IN_][j % IN_] = xsrc[j];
        for (int j = tid; j < CH * (H_ - IN_); j += TPB)
            hist[j / (H_ - IN_)][IN_ + j % (H_ - IN_)] = 0.f;
        __syncthreads();

        for (int l = 0; l < L_; ++l) {
            // ---- 20 float4 of packed weights into named, pinned registers ----
            const float4* wp = (const float4*)wbuf + (size_t)l * 20 * TPB + tid;
#define WD(N) float4 w##N = wp[(size_t)N * TPB];
            WD(0) WD(1) WD(2) WD(3) WD(4) WD(5) WD(6) WD(7) WD(8) WD(9)
            WD(10) WD(11) WD(12) WD(13) WD(14) WD(15) WD(16) WD(17) WD(18) WD(19)
#undef WD
            PIN4(w0);  PIN4(w1);  PIN4(w2);  PIN4(w3);  PIN4(w4);
            PIN4(w5);  PIN4(w6);  PIN4(w7);  PIN4(w8);  PIN4(w9);
            PIN4(w10); PIN4(w11); PIN4(w12); PIN4(w13); PIN4(w14);
            PIN4(w15); PIN4(w16); PIN4(w17); PIN4(w18); PIN4(w19);

            const float bi = (s == 0) ? bbuf[l * G4 + 0 * H_ + e] : 0.f;
            const float bf = (s == 0) ? bbuf[l * G4 + 1 * H_ + e] : 0.f;
            const float bg = (s == 0) ? bbuf[l * G4 + 2 * H_ + e] : 0.f;
            const float bo = (s == 0) ? bbuf[l * G4 + 3 * H_ + e] : 0.f;

            if (tid < H_) hs[0][tid] = hstate[l][tid];
            float creg = cstate[l][e];       // broadcast read, replicated in 8 lanes
            __syncthreads();

            int par = 0;
            float hprev = 0.f;
            for (int t = 0; t < CH; ++t) {
                if (t) { if (s == 0) hist[t - 1][e] = hprev; }  // deferred h-history write

                const float* bp = (s < 4) ? hist[t] : hs[par];
                const float4* vp = (const float4*)(bp + koff);
                float4 v0 = vp[0], v1 = vp[1], v2 = vp[2], v3 = vp[3], v4 = vp[4];

                float aI = bi, aF = bf, aG = bg, aO = bo;
#define FM(acc, W, V) acc += W.x * V.x; acc += W.y * V.y; acc += W.z * V.z; acc += W.w * V.w;
                FM(aI, w0,  v0) FM(aI, w1,  v1) FM(aI, w2,  v2) FM(aI, w3,  v3) FM(aI, w4,  v4)
                FM(aF, w5,  v0) FM(aF, w6,  v1) FM(aF, w7,  v2) FM(aF, w8,  v3) FM(aF, w9,  v4)
                FM(aG, w10, v0) FM(aG, w11, v1) FM(aG, w12, v2) FM(aG, w13, v3) FM(aG, w14, v4)
                FM(aO, w15, v0) FM(aO, w16, v1) FM(aO, w17, v2) FM(aO, w18, v3) FM(aO, w19, v4)
#undef FM
                aI = reduce8(aI); aF = reduce8(aF); aG = reduce8(aG); aO = reduce8(aO);

                float gi = sigm(aI), gf = sigm(aF), gg = tanhfast(aG), go = sigm(aO);
                creg = gf * creg + gi * gg;
                float h = go * tanhfast(creg);

                if (s == 0) hs[par ^ 1][e] = h;
                hprev = h;
                __syncthreads();
                par ^= 1;
            }

            if (s == 0) {
                hist[CH - 1][e] = hprev;     // safe: all reads of hist[CH-1] done
                hstate[l][e] = hprev;
                cstate[l][e] = creg;
            }
            __syncthreads();
        }
    }

    // fc on the final hidden state
    if (tid < NC_) {
        float acc = fcb[tid];
#pragma unroll
        for (int j = 0; j < H_; ++j) acc += fcw[tid * H_ + j] * hstate[L_ - 1][j];
        out[b * NC_ + tid] = acc;
    }
}

extern "C" void kernel_launch(void* const* d_in, const int* in_sizes, int n_in,
                              void* d_out, int out_size, void* d_ws, size_t ws_size,
                              hipStream_t stream) {
    const float* x    = (const float*)d_in[0];
    const float* Wih0 = (const float*)d_in[1];
    const float* WihR = (const float*)d_in[2];
    const float* Whh  = (const float*)d_in[3];
    const float* bih  = (const float*)d_in[4];
    const float* bhh  = (const float*)d_in[5];
    const float* fcw  = (const float*)d_in[6];
    const float* fcb  = (const float*)d_in[7];

    float* wbuf = (float*)d_ws;              // 512000 floats
    float* bbuf = wbuf + NWF;                // 3200 floats

    prep_kernel<<<dim3((NWF + 255) / 256), dim3(256), 0, stream>>>(
        Wih0, WihR, Whh, bih, bhh, wbuf, bbuf);

    lstm_stack_kernel<<<dim3(B_), dim3(TPB), 0, stream>>>(
        x, wbuf, bbuf, fcw, fcb, (float*)d_out);
}